// Round 8
// baseline (239.649 us; speedup 1.0000x reference)
//
#include <hip/hip_runtime.h>
#include <cstddef>

// B=2, L=2048, DIM=1024, H=16, DH=64. M = B*L = 4096.
// cvt -> QKV NT-GEMM (V transposed) -> mask pack -> flash attn (sigma-K, K=32 PV) -> out GEMM (+merge).

typedef __bf16 bf16x8 __attribute__((ext_vector_type(8)));
typedef __bf16 bf16x4 __attribute__((ext_vector_type(4)));
typedef float  f32x4  __attribute__((ext_vector_type(4)));
typedef short  s16x4  __attribute__((ext_vector_type(4)));

__device__ __forceinline__ void async16(const __bf16* g, __bf16* l) {
  __builtin_amdgcn_global_load_lds((const __attribute__((address_space(1))) unsigned int*)g,
                                   (__attribute__((address_space(3))) unsigned int*)l, 16, 0, 0);
}

// ---------------- fp32 -> bf16 conversion; Wq pre-scaled by 0.125*log2(e) ----------------
__global__ __launch_bounds__(256) void cvt_all(
    const float* __restrict__ X,  const float* __restrict__ Wq, const float* __restrict__ Wk,
    const float* __restrict__ Wv, const float* __restrict__ Wo,
    __bf16* __restrict__ oX,  __bf16* __restrict__ oWq, __bf16* __restrict__ oWk,
    __bf16* __restrict__ oWv, __bf16* __restrict__ oWo) {
  int i = blockIdx.x * 256 + threadIdx.x;  // float4 index, total 2097152
  const float* s; __bf16* d; int off; float sc = 1.0f;
  if (i < 1048576)      { s = X;  d = oX;  off = i; }
  else if (i < 1310720) { s = Wq; d = oWq; off = i - 1048576; sc = 0.18033688011112042f; }
  else if (i < 1572864) { s = Wk; d = oWk; off = i - 1310720; }
  else if (i < 1835008) { s = Wv; d = oWv; off = i - 1572864; }
  else                  { s = Wo; d = oWo; off = i - 1835008; }
  float4 v = ((const float4*)s)[off];
  bf16x4 o;
  o.x = (__bf16)(v.x * sc); o.y = (__bf16)(v.y * sc);
  o.z = (__bf16)(v.z * sc); o.w = (__bf16)(v.w * sc);
  ((bf16x4*)d)[off] = o;
}

// ---------------- mask bit-pack: pm[b][kt][q] = ballot over 64 kv ----------------
__global__ __launch_bounds__(256) void mask_pack(const int* __restrict__ m,
                                                 unsigned long long* __restrict__ pm) {
  int w = blockIdx.x * 4 + (threadIdx.x >> 6);   // word idx over (b,q,kt), 131072 total
  int lane = threadIdx.x & 63;
  unsigned long long bits = __ballot(m[(size_t)w * 64 + lane] != 0);
  int b = w >> 16, q = (w >> 5) & 2047, kt = w & 31;
  if (lane == 0) pm[((size_t)b << 16) + kt * 2048 + q] = bits;
}

// ---------------- 128x128xK NT GEMM tile (K=1024, BK=32), m97-style + XOR swizzle ----
__device__ __forceinline__ void gemm128(const __bf16* __restrict__ A, const __bf16* __restrict__ B,
                                        __bf16* __restrict__ C, int lda, int ldb, int ldc,
                                        int m0, int n0, __bf16* As, __bf16* Bs) {
  const int tid = threadIdx.x;
  const int wave = tid >> 6, lane = tid & 63, quad = lane >> 4, l15 = lane & 15;
  const int wm = (wave & 1) * 64, wn = (wave >> 1) * 64;
  const f32x4 z4 = {0.f, 0.f, 0.f, 0.f};
  f32x4 acc[4][4];
#pragma unroll
  for (int i = 0; i < 4; ++i)
#pragma unroll
    for (int j = 0; j < 4; ++j) acc[i][j] = z4;

  for (int k0 = 0; k0 < 1024; k0 += 32) {
#pragma unroll
    for (int s = 0; s < 2; ++s) {
      int p = (wave * 2 + s) * 64 + lane;
      int r = p >> 2;
      int cc = (p & 3) ^ ((r >> 1) & 3);
      async16(A + (size_t)(m0 + r) * lda + (k0 + cc * 8), As + (wave * 2 + s) * 512);
      async16(B + (size_t)(n0 + r) * ldb + (k0 + cc * 8), Bs + (wave * 2 + s) * 512);
    }
    __syncthreads();
    bf16x8 af[4], bfr[4];
#pragma unroll
    for (int i = 0; i < 4; ++i) {
      int r = wm + i * 16 + l15;
      int cc = quad ^ ((r >> 1) & 3);
      af[i] = *(const bf16x8*)(As + r * 32 + cc * 8);
    }
#pragma unroll
    for (int j = 0; j < 4; ++j) {
      int r = wn + j * 16 + l15;
      int cc = quad ^ ((r >> 1) & 3);
      bfr[j] = *(const bf16x8*)(Bs + r * 32 + cc * 8);
    }
#pragma unroll
    for (int i = 0; i < 4; ++i)
#pragma unroll
      for (int j = 0; j < 4; ++j)
        acc[i][j] = __builtin_amdgcn_mfma_f32_16x16x32_bf16(af[i], bfr[j], acc[i][j], 0, 0, 0);
    __syncthreads();
  }
#pragma unroll
  for (int i = 0; i < 4; ++i)
#pragma unroll
    for (int j = 0; j < 4; ++j)
#pragma unroll
      for (int rr = 0; rr < 4; ++rr) {
        int row = m0 + wm + i * 16 + quad * 4 + rr;
        int col = n0 + wn + j * 16 + l15;
        C[(size_t)row * ldc + col] = (__bf16)acc[i][j][rr];
      }
}

__global__ __launch_bounds__(256) void qkv_gemm(const __bf16* __restrict__ X,
                                                const __bf16* __restrict__ Wq,
                                                const __bf16* __restrict__ Wk,
                                                const __bf16* __restrict__ Wv,
                                                __bf16* __restrict__ Q, __bf16* __restrict__ K,
                                                __bf16* __restrict__ Vt) {
  __shared__ __bf16 As[4096], Bs[4096];
  int t = blockIdx.x, z = blockIdx.y;
  if (z < 2) {
    int mt = t & 31, nt = t >> 5;
    gemm128(X, z ? Wk : Wq, z ? K : Q, 1024, 1024, 1024, mt * 128, nt * 128, As, Bs);
  } else {
    int mt = t & 7, nt = t >> 3;
    gemm128(Wv, X, Vt, 1024, 1024, 4096, mt * 128, nt * 128, As, Bs);
  }
}

// ---------------- out GEMM with fused merge: A = (c0+c1)/(l0+l1) staged via VGPR ----------
__global__ __launch_bounds__(256) void out_gemm(const __bf16* __restrict__ c0,
                                                const __bf16* __restrict__ c1,
                                                const float* __restrict__ lp,
                                                const __bf16* __restrict__ Wo,
                                                float* __restrict__ Out) {
  __shared__ __bf16 As[4096], Bs[4096];
  const int t = blockIdx.x;
  const int mt = t & 31, nt = t >> 5;
  const int m0 = mt * 128, n0 = nt * 128;
  const int tid = threadIdx.x;
  const int wave = tid >> 6, lane = tid & 63, quad = lane >> 4, l15 = lane & 15;
  const int wm = (wave & 1) * 64, wn = (wave >> 1) * 64;
  const f32x4 z4 = {0.f, 0.f, 0.f, 0.f};
  f32x4 acc[4][4];
#pragma unroll
  for (int i = 0; i < 4; ++i)
#pragma unroll
    for (int j = 0; j < 4; ++j) acc[i][j] = z4;

  for (int k0 = 0; k0 < 1024; k0 += 32) {
    const int h = k0 >> 6;
#pragma unroll
    for (int s = 0; s < 2; ++s) {
      int p = (wave * 2 + s) * 64 + lane;
      int r = p >> 2;
      int cc = (p & 3) ^ ((r >> 1) & 3);
      async16(Wo + (size_t)(n0 + r) * 1024 + (k0 + cc * 8), Bs + (wave * 2 + s) * 512);
      size_t off = (size_t)(m0 + r) * 1024 + k0 + cc * 8;
      bf16x8 a  = *(const bf16x8*)(c0 + off);
      bf16x8 b2 = *(const bf16x8*)(c1 + off);
      float inv = 1.0f / (lp[(m0 + r) * 16 + h] + lp[65536 + (m0 + r) * 16 + h]);
      bf16x8 o;
#pragma unroll
      for (int j = 0; j < 8; ++j) o[j] = (__bf16)(((float)a[j] + (float)b2[j]) * inv);
      *(bf16x8*)(As + p * 8) = o;
    }
    __syncthreads();
    bf16x8 af[4], bfr[4];
#pragma unroll
    for (int i = 0; i < 4; ++i) {
      int r = wm + i * 16 + l15;
      int cc = quad ^ ((r >> 1) & 3);
      af[i] = *(const bf16x8*)(As + r * 32 + cc * 8);
    }
#pragma unroll
    for (int j = 0; j < 4; ++j) {
      int r = wn + j * 16 + l15;
      int cc = quad ^ ((r >> 1) & 3);
      bfr[j] = *(const bf16x8*)(Bs + r * 32 + cc * 8);
    }
#pragma unroll
    for (int i = 0; i < 4; ++i)
#pragma unroll
      for (int j = 0; j < 4; ++j)
        acc[i][j] = __builtin_amdgcn_mfma_f32_16x16x32_bf16(af[i], bfr[j], acc[i][j], 0, 0, 0);
    __syncthreads();
  }
#pragma unroll
  for (int i = 0; i < 4; ++i)
#pragma unroll
    for (int j = 0; j < 4; ++j)
#pragma unroll
      for (int rr = 0; rr < 4; ++rr) {
        int row = m0 + wm + i * 16 + quad * 4 + rr;
        int col = n0 + wn + j * 16 + l15;
        Out[(size_t)row * 1024 + col] = acc[i][j][rr];
      }
}

// ---------------- flash attention: sigma-permuted K rows, K=32 PV, LDS dbuf ----------------
// Block = 128 q rows of one (b,h) x half the kv range; grid 1024 -> 4 blocks/CU.
// K staged with row permutation sigma(r): bits (kf1 kf0 q1 q0 r1 r0) -> (kf1 q1 q0 kf0 r1 r0).
// Then a quad's four St C-frags cover kv {quad*8..+7} contiguously == A-operand layout of
// mfma_f32_16x16x32_bf16 -> PV is 8 (not 16) MFMAs per strip and V frags are b128 reads
// whose XOR-swizzled pattern hits 8 disjoint 4-bank groups (zero conflict).
// Fixed-max softmax (C folded into Wq scale + acc bias) -> pure sum; halves merged in out_gemm.
__global__ __launch_bounds__(256, 4) void attn_kernel(
    const __bf16* __restrict__ Q, const __bf16* __restrict__ K,
    const __bf16* __restrict__ Vt, const unsigned long long* __restrict__ pm,
    __bf16* __restrict__ c0, __bf16* __restrict__ c1, float* __restrict__ lp) {
  __shared__ __bf16 Ks[2][4096];  // [row r][d chunks, XOR-swizzled], rows sigma-permuted
  __shared__ __bf16 Vs[2][4096];  // [d][kv chunks, XOR-swizzled]
  const int tid = threadIdx.x;
  const int wave = tid >> 6, lane = tid & 63, quad = lane >> 4, l15 = lane & 15;
  const int id = blockIdx.x;
  const int hb = id & 31, h = hb & 15, b = hb >> 4;
  const int kvh = (id >> 5) & 1, qt = id >> 6;
  const int qw = qt * 128 + wave * 32;  // this wave's 32 q rows
  const int kt0 = kvh * 16;             // this block's 16 kv tiles

  // Q B-frags for both strips: B[n=q=l15][k=d=quad*8+j]
  bf16x8 aq[2][2];
#pragma unroll
  for (int st = 0; st < 2; ++st) {
    const __bf16* Qp = Q + (size_t)(b * 2048 + qw + st * 16 + l15) * 1024 + h * 64 + quad * 8;
    aq[st][0] = *(const bf16x8*)Qp;
    aq[st][1] = *(const bf16x8*)(Qp + 32);
  }

  const unsigned long long* Pm = pm + ((size_t)b << 16) + qw + l15;

  auto stage = [&](int buf, int kv0) {
#pragma unroll
    for (int s = 0; s < 2; ++s) {
      int p = s * 256 + wave * 64 + lane;
      int r = p >> 3, c = (p & 7) ^ (r & 7);
      int sr = (r & 0x20) | ((r & 0x0C) << 1) | ((r & 0x10) >> 2) | (r & 3);  // sigma(r)
      async16(K  + (size_t)(b * 2048 + kv0 + sr) * 1024 + h * 64 + c * 8,
              &Ks[buf][(s * 256 + wave * 64) * 8]);
      async16(Vt + (size_t)(h * 64 + r) * 4096 + b * 2048 + kv0 + c * 8,
              &Vs[buf][(s * 256 + wave * 64) * 8]);
    }
  };

  stage(0, kt0 * 64);
  unsigned long long mw[2] = {Pm[(size_t)kt0 * 2048], Pm[(size_t)kt0 * 2048 + 16]};

  const f32x4 z4 = {0.f, 0.f, 0.f, 0.f};
  const f32x4 cbias = {-28.853900817779268f, -28.853900817779268f,
                       -28.853900817779268f, -28.853900817779268f};
  const __bf16 one_bf = (__bf16)1.0f;
  const bf16x8 vOnes8 = {one_bf, one_bf, one_bf, one_bf, one_bf, one_bf, one_bf, one_bf};
  f32x4 acc[2][4];
#pragma unroll
  for (int st = 0; st < 2; ++st)
#pragma unroll
    for (int dt = 0; dt < 4; ++dt) acc[st][dt] = z4;
  f32x4 acc_l[2] = {z4, z4};

  for (int t = 0; t < 16; ++t) {
    __syncthreads();  // staging of buf t&1 complete; reads of previous buf done
    if (t < 15) stage((t & 1) ^ 1, (kt0 + t + 1) * 64);

    const __bf16* Kc = Ks[t & 1];
    const __bf16* Vc = Vs[t & 1];

    // V b128 frags, shared by both strips: B[n=d=l15][k=kv=quad*8+j], kv base kp*32
    bf16x8 vB[4][2];
#pragma unroll
    for (int dt = 0; dt < 4; ++dt) {
      int d = dt * 16 + l15;
#pragma unroll
      for (int kp = 0; kp < 2; ++kp)
        vB[dt][kp] = *(const bf16x8*)(Vc + d * 64 + (((kp * 4 + quad) ^ (d & 7)) * 8));
    }

#pragma unroll
    for (int st = 0; st < 2; ++st) {
      // St = K·Q^T + bias (rows = sigma-permuted kv)
      f32x4 s4[4];
#pragma unroll
      for (int jt = 0; jt < 4; ++jt) {
        int r = jt * 16 + l15;
        bf16x8 k0 = *(const bf16x8*)(Kc + r * 64 + ((quad ^ (r & 7)) * 8));
        bf16x8 k1 = *(const bf16x8*)(Kc + r * 64 + (((4 + quad) ^ (r & 7)) * 8));
        f32x4 tt = cbias;
        tt = __builtin_amdgcn_mfma_f32_16x16x32_bf16(k0, aq[st][0], tt, 0, 0, 0);
        tt = __builtin_amdgcn_mfma_f32_16x16x32_bf16(k1, aq[st][1], tt, 0, 0, 0);
        s4[jt] = tt;
      }

      unsigned long long wq = mw[st] >> (quad * 8);
      if (t < 15) mw[st] = Pm[(size_t)(kt0 + t + 1) * 2048 + st * 16];
      unsigned lo32 = (unsigned)wq, hi32 = (unsigned)(wq >> 32);

      // softmax + PV: P A-frag kv=quad*8+j assembled from frag pair (2kp, 2kp+1)
#pragma unroll
      for (int kp = 0; kp < 2; ++kp) {
        unsigned bw = kp ? hi32 : lo32;
        bf16x8 p8;
#pragma unroll
        for (int j = 0; j < 8; ++j) {
          float e = (bw & (1u << j)) ? s4[kp * 2 + (j >> 2)][j & 3] : -1e30f;
          p8[j] = (__bf16)__builtin_amdgcn_exp2f(e);
        }
        acc_l[st] = __builtin_amdgcn_mfma_f32_16x16x32_bf16(p8, vOnes8, acc_l[st], 0, 0, 0);
#pragma unroll
        for (int dt = 0; dt < 4; ++dt)
          acc[st][dt] = __builtin_amdgcn_mfma_f32_16x16x32_bf16(p8, vB[dt][kp], acc[st][dt], 0, 0, 0);
      }
    }
  }

  // epilogue: store UNNORMALIZED bf16 partial ctx + f32 partial l (merged in out_gemm)
  __bf16* cout = kvh ? c1 : c0;
  float* lout = lp + kvh * 65536;
#pragma unroll
  for (int st = 0; st < 2; ++st) {
#pragma unroll
    for (int dt = 0; dt < 4; ++dt)
#pragma unroll
      for (int rr = 0; rr < 4; ++rr)
        cout[(size_t)(b * 2048 + qw + st * 16 + quad * 4 + rr) * 1024 + h * 64 + dt * 16 + l15] =
            (__bf16)acc[st][dt][rr];
    if (l15 == 0) {
#pragma unroll
      for (int rr = 0; rr < 4; ++rr)
        lout[(size_t)(b * 2048 + qw + st * 16 + quad * 4 + rr) * 16 + h] = acc_l[st][rr];
    }
  }
}

extern "C" void kernel_launch(void* const* d_in, const int* in_sizes, int n_in,
                              void* d_out, int out_size, void* d_ws, size_t ws_size,
                              hipStream_t stream) {
  const float* X  = (const float*)d_in[0];
  const int* mask = (const int*)d_in[1];
  const float* Wq = (const float*)d_in[2];
  const float* Wk = (const float*)d_in[3];
  const float* Wv = (const float*)d_in[4];
  const float* Wo = (const float*)d_in[5];

  __bf16* w   = (__bf16*)d_ws;
  __bf16* Xbf = w;                  // 4096*1024
  __bf16* Wqb = Xbf + 4194304;      // 1024*1024 each
  __bf16* Wkb = Wqb + 1048576;
  __bf16* Wvb = Wkb + 1048576;
  __bf16* Wob = Wvb + 1048576;
  __bf16* Qb  = Wob + 1048576;      // 4096*1024
  __bf16* Kb  = Qb + 4194304;
  __bf16* Vtb = Kb + 4194304;       // 1024*4096 (transposed V)
  __bf16* Ctx = Vtb + 4194304;      // 4096*1024 (half-0 partial)
  // dead-region reuse after qkv_gemm: pm in Wqb (1MB), l partials in Wkb (512KB),
  // ctx partial half-1 in Xbf (8MB).
  unsigned long long* pmt = (unsigned long long*)Wqb;
  float* lpart = (float*)Wkb;       // [2][4096][16] f32
  __bf16* c1 = Xbf;

  cvt_all<<<8192, 256, 0, stream>>>(X, Wq, Wk, Wv, Wo, Xbf, Wqb, Wkb, Wvb, Wob);
  qkv_gemm<<<dim3(256, 3), 256, 0, stream>>>(Xbf, Wqb, Wkb, Wvb, Qb, Kb, Vtb);
  mask_pack<<<32768, 256, 0, stream>>>(mask, pmt);
  attn_kernel<<<1024, 256, 0, stream>>>(Qb, Kb, Vtb, pmt, Ctx, c1, lpart);
  out_gemm<<<256, 256, 0, stream>>>(Ctx, c1, lpart, Wob, (float*)d_out);
}

// Round 9
// 221.723 us; speedup vs baseline: 1.0809x; 1.0809x over previous
//
#include <hip/hip_runtime.h>
#include <cstddef>

// B=2, L=2048, DIM=1024, H=16, DH=64. M = B*L = 4096.
// prep (cvt + mask pack) -> QKV NT-GEMM (V transposed) -> flash attn (sigma-K) -> merge -> out GEMM.

typedef __bf16 bf16x8 __attribute__((ext_vector_type(8)));
typedef __bf16 bf16x4 __attribute__((ext_vector_type(4)));
typedef float  f32x4  __attribute__((ext_vector_type(4)));
typedef short  s16x4  __attribute__((ext_vector_type(4)));

__device__ __forceinline__ void async16(const __bf16* g, __bf16* l) {
  __builtin_amdgcn_global_load_lds((const __attribute__((address_space(1))) unsigned int*)g,
                                   (__attribute__((address_space(3))) unsigned int*)l, 16, 0, 0);
}

// ---------------- prep: fp32->bf16 cvt (blocks 0..8191) + mask bit-pack (rest) ----------
// Wq pre-scaled by 0.125*log2(e) (softmax scale folded into Q).
__global__ __launch_bounds__(256) void prep_kernel(
    const float* __restrict__ X,  const float* __restrict__ Wq, const float* __restrict__ Wk,
    const float* __restrict__ Wv, const float* __restrict__ Wo, const int* __restrict__ m,
    __bf16* __restrict__ oX,  __bf16* __restrict__ oWq, __bf16* __restrict__ oWk,
    __bf16* __restrict__ oWv, __bf16* __restrict__ oWo, unsigned long long* __restrict__ pm) {
  if (blockIdx.x < 8192) {
    int i = blockIdx.x * 256 + threadIdx.x;  // float4 index, total 2097152
    const float* s; __bf16* d; int off; float sc = 1.0f;
    if (i < 1048576)      { s = X;  d = oX;  off = i; }
    else if (i < 1310720) { s = Wq; d = oWq; off = i - 1048576; sc = 0.18033688011112042f; }
    else if (i < 1572864) { s = Wk; d = oWk; off = i - 1310720; }
    else if (i < 1835008) { s = Wv; d = oWv; off = i - 1572864; }
    else                  { s = Wo; d = oWo; off = i - 1835008; }
    float4 v = ((const float4*)s)[off];
    bf16x4 o;
    o.x = (__bf16)(v.x * sc); o.y = (__bf16)(v.y * sc);
    o.z = (__bf16)(v.z * sc); o.w = (__bf16)(v.w * sc);
    ((bf16x4*)d)[off] = o;
  } else {
    int w = (blockIdx.x - 8192) * 4 + (threadIdx.x >> 6);  // word idx over (b,q,kt), 131072
    int lane = threadIdx.x & 63;
    unsigned long long bits = __ballot(m[(size_t)w * 64 + lane] != 0);
    int b = w >> 16, q = (w >> 5) & 2047, kt = w & 31;
    if (lane == 0) pm[((size_t)b << 16) + kt * 2048 + q] = bits;
  }
}

// ---------------- 128x128xK NT GEMM tile (K=1024, BK=32), m97-style + XOR swizzle ----
template<bool OUT_BF16>
__device__ __forceinline__ void gemm128(const __bf16* __restrict__ A, const __bf16* __restrict__ B,
                                        void* __restrict__ C, int lda, int ldb, int ldc,
                                        int m0, int n0, __bf16* As, __bf16* Bs) {
  const int tid = threadIdx.x;
  const int wave = tid >> 6, lane = tid & 63, quad = lane >> 4, l15 = lane & 15;
  const int wm = (wave & 1) * 64, wn = (wave >> 1) * 64;
  const f32x4 z4 = {0.f, 0.f, 0.f, 0.f};
  f32x4 acc[4][4];
#pragma unroll
  for (int i = 0; i < 4; ++i)
#pragma unroll
    for (int j = 0; j < 4; ++j) acc[i][j] = z4;

  for (int k0 = 0; k0 < 1024; k0 += 32) {
#pragma unroll
    for (int s = 0; s < 2; ++s) {
      int p = (wave * 2 + s) * 64 + lane;
      int r = p >> 2;
      int cc = (p & 3) ^ ((r >> 1) & 3);
      async16(A + (size_t)(m0 + r) * lda + (k0 + cc * 8), As + (wave * 2 + s) * 512);
      async16(B + (size_t)(n0 + r) * ldb + (k0 + cc * 8), Bs + (wave * 2 + s) * 512);
    }
    __syncthreads();
    bf16x8 af[4], bfr[4];
#pragma unroll
    for (int i = 0; i < 4; ++i) {
      int r = wm + i * 16 + l15;
      int cc = quad ^ ((r >> 1) & 3);
      af[i] = *(const bf16x8*)(As + r * 32 + cc * 8);
    }
#pragma unroll
    for (int j = 0; j < 4; ++j) {
      int r = wn + j * 16 + l15;
      int cc = quad ^ ((r >> 1) & 3);
      bfr[j] = *(const bf16x8*)(Bs + r * 32 + cc * 8);
    }
#pragma unroll
    for (int i = 0; i < 4; ++i)
#pragma unroll
      for (int j = 0; j < 4; ++j)
        acc[i][j] = __builtin_amdgcn_mfma_f32_16x16x32_bf16(af[i], bfr[j], acc[i][j], 0, 0, 0);
    __syncthreads();
  }
#pragma unroll
  for (int i = 0; i < 4; ++i)
#pragma unroll
    for (int j = 0; j < 4; ++j)
#pragma unroll
      for (int rr = 0; rr < 4; ++rr) {
        int row = m0 + wm + i * 16 + quad * 4 + rr;
        int col = n0 + wn + j * 16 + l15;
        if (OUT_BF16) ((__bf16*)C)[(size_t)row * ldc + col] = (__bf16)acc[i][j][rr];
        else          ((float*)C)[(size_t)row * ldc + col]  = acc[i][j][rr];
      }
}

__global__ __launch_bounds__(256) void qkv_gemm(const __bf16* __restrict__ X,
                                                const __bf16* __restrict__ Wq,
                                                const __bf16* __restrict__ Wk,
                                                const __bf16* __restrict__ Wv,
                                                __bf16* __restrict__ Q, __bf16* __restrict__ K,
                                                __bf16* __restrict__ Vt) {
  __shared__ __bf16 As[4096], Bs[4096];
  int t = blockIdx.x, z = blockIdx.y;
  if (z < 2) {
    int mt = t & 31, nt = t >> 5;
    gemm128<true>(X, z ? Wk : Wq, z ? K : Q, 1024, 1024, 1024, mt * 128, nt * 128, As, Bs);
  } else {
    int mt = t & 7, nt = t >> 3;
    gemm128<true>(Wv, X, Vt, 1024, 1024, 4096, mt * 128, nt * 128, As, Bs);
  }
}

__global__ __launch_bounds__(256) void out_gemm(const __bf16* __restrict__ Ctx,
                                                const __bf16* __restrict__ Wo,
                                                float* __restrict__ Out) {
  __shared__ __bf16 As[4096], Bs[4096];
  int t = blockIdx.x;
  int mt = t & 31, nt = t >> 5;
  gemm128<false>(Ctx, Wo, Out, 1024, 1024, 1024, mt * 128, nt * 128, As, Bs);
}

// ---------------- merge halves: Ctx = (c0+c1)/(l0+l1), bf16 out ----------------
__global__ __launch_bounds__(256) void merge_kernel(const __bf16* __restrict__ c0,
                                                    const __bf16* __restrict__ c1,
                                                    const float* __restrict__ lp,
                                                    __bf16* __restrict__ Ctx) {
  int i = blockIdx.x * 256 + threadIdx.x;  // bf16x8 chunk, 524288 total
  int base = i * 8;
  int row = base >> 10, h = (base >> 6) & 15;
  float inv = 1.0f / (lp[row * 16 + h] + lp[65536 + row * 16 + h]);
  bf16x8 a = ((const bf16x8*)c0)[i];
  bf16x8 bb = ((const bf16x8*)c1)[i];
  bf16x8 o;
#pragma unroll
  for (int r = 0; r < 8; ++r) o[r] = (__bf16)(((float)a[r] + (float)bb[r]) * inv);
  ((bf16x8*)Ctx)[i] = o;
}

// ---------------- flash attention: sigma-permuted K rows, K=32 PV, LDS dbuf ----------------
// Block = 128 q rows of one (b,h) x half the kv range; grid 1024 -> 4 blocks/CU.
// K staged with row permutation sigma(r): bits (kf1 kf0 q1 q0 r1 r0) -> (kf1 q1 q0 kf0 r1 r0).
// A quad's four St C-frags then cover kv {quad*8..+7} contiguously == A-operand layout of
// mfma_f32_16x16x32_bf16 -> PV is 8 MFMAs per strip; V frags are b128 reads hitting 8
// disjoint 4-bank groups (0 conflicts, verified R8). Fixed-max softmax (C folded into Wq
// scale + acc bias) -> pure sum; halves merged in merge_kernel.
__global__ __launch_bounds__(256, 4) void attn_kernel(
    const __bf16* __restrict__ Q, const __bf16* __restrict__ K,
    const __bf16* __restrict__ Vt, const unsigned long long* __restrict__ pm,
    __bf16* __restrict__ c0, __bf16* __restrict__ c1, float* __restrict__ lp) {
  __shared__ __bf16 Ks[2][4096];  // [row r][d chunks, XOR-swizzled], rows sigma-permuted
  __shared__ __bf16 Vs[2][4096];  // [d][kv chunks, XOR-swizzled]
  const int tid = threadIdx.x;
  const int wave = tid >> 6, lane = tid & 63, quad = lane >> 4, l15 = lane & 15;
  const int id = blockIdx.x;
  const int hb = id & 31, h = hb & 15, b = hb >> 4;
  const int kvh = (id >> 5) & 1, qt = id >> 6;
  const int qw = qt * 128 + wave * 32;  // this wave's 32 q rows
  const int kt0 = kvh * 16;             // this block's 16 kv tiles

  // Q B-frags for both strips: B[n=q=l15][k=d=quad*8+j]
  bf16x8 aq[2][2];
#pragma unroll
  for (int st = 0; st < 2; ++st) {
    const __bf16* Qp = Q + (size_t)(b * 2048 + qw + st * 16 + l15) * 1024 + h * 64 + quad * 8;
    aq[st][0] = *(const bf16x8*)Qp;
    aq[st][1] = *(const bf16x8*)(Qp + 32);
  }

  const unsigned long long* Pm = pm + ((size_t)b << 16) + qw + l15;

  auto stage = [&](int buf, int kv0) {
#pragma unroll
    for (int s = 0; s < 2; ++s) {
      int p = s * 256 + wave * 64 + lane;
      int r = p >> 3, c = (p & 7) ^ (r & 7);
      int sr = (r & 0x20) | ((r & 0x0C) << 1) | ((r & 0x10) >> 2) | (r & 3);  // sigma(r)
      async16(K  + (size_t)(b * 2048 + kv0 + sr) * 1024 + h * 64 + c * 8,
              &Ks[buf][(s * 256 + wave * 64) * 8]);
      async16(Vt + (size_t)(h * 64 + r) * 4096 + b * 2048 + kv0 + c * 8,
              &Vs[buf][(s * 256 + wave * 64) * 8]);
    }
  };

  stage(0, kt0 * 64);
  unsigned long long mw[2] = {Pm[(size_t)kt0 * 2048], Pm[(size_t)kt0 * 2048 + 16]};

  const f32x4 z4 = {0.f, 0.f, 0.f, 0.f};
  const f32x4 cbias = {-28.853900817779268f, -28.853900817779268f,
                       -28.853900817779268f, -28.853900817779268f};
  const __bf16 one_bf = (__bf16)1.0f;
  const bf16x8 vOnes8 = {one_bf, one_bf, one_bf, one_bf, one_bf, one_bf, one_bf, one_bf};
  f32x4 acc[2][4];
#pragma unroll
  for (int st = 0; st < 2; ++st)
#pragma unroll
    for (int dt = 0; dt < 4; ++dt) acc[st][dt] = z4;
  f32x4 acc_l[2] = {z4, z4};

  for (int t = 0; t < 16; ++t) {
    __syncthreads();  // staging of buf t&1 complete; reads of previous buf done
    if (t < 15) stage((t & 1) ^ 1, (kt0 + t + 1) * 64);

    const __bf16* Kc = Ks[t & 1];
    const __bf16* Vc = Vs[t & 1];

    // V b128 frags, shared by both strips: B[n=d=l15][k=kv=quad*8+j], kv base kp*32
    bf16x8 vB[4][2];
#pragma unroll
    for (int dt = 0; dt < 4; ++dt) {
      int d = dt * 16 + l15;
#pragma unroll
      for (int kp = 0; kp < 2; ++kp)
        vB[dt][kp] = *(const bf16x8*)(Vc + d * 64 + (((kp * 4 + quad) ^ (d & 7)) * 8));
    }

#pragma unroll
    for (int st = 0; st < 2; ++st) {
      // St = K·Q^T + bias (rows = sigma-permuted kv)
      f32x4 s4[4];
#pragma unroll
      for (int jt = 0; jt < 4; ++jt) {
        int r = jt * 16 + l15;
        bf16x8 k0 = *(const bf16x8*)(Kc + r * 64 + ((quad ^ (r & 7)) * 8));
        bf16x8 k1 = *(const bf16x8*)(Kc + r * 64 + (((4 + quad) ^ (r & 7)) * 8));
        f32x4 tt = cbias;
        tt = __builtin_amdgcn_mfma_f32_16x16x32_bf16(k0, aq[st][0], tt, 0, 0, 0);
        tt = __builtin_amdgcn_mfma_f32_16x16x32_bf16(k1, aq[st][1], tt, 0, 0, 0);
        s4[jt] = tt;
      }

      unsigned long long wq = mw[st] >> (quad * 8);
      if (t < 15) mw[st] = Pm[(size_t)(kt0 + t + 1) * 2048 + st * 16];
      unsigned lo32 = (unsigned)wq, hi32 = (unsigned)(wq >> 32);

      // softmax + PV: P A-frag kv=quad*8+j assembled from frag pair (2kp, 2kp+1)
#pragma unroll
      for (int kp = 0; kp < 2; ++kp) {
        unsigned bw = kp ? hi32 : lo32;
        bf16x8 p8;
#pragma unroll
        for (int j = 0; j < 8; ++j) {
          float e = (bw & (1u << j)) ? s4[kp * 2 + (j >> 2)][j & 3] : -1e30f;
          p8[j] = (__bf16)__builtin_amdgcn_exp2f(e);
        }
        acc_l[st] = __builtin_amdgcn_mfma_f32_16x16x32_bf16(p8, vOnes8, acc_l[st], 0, 0, 0);
#pragma unroll
        for (int dt = 0; dt < 4; ++dt)
          acc[st][dt] = __builtin_amdgcn_mfma_f32_16x16x32_bf16(p8, vB[dt][kp], acc[st][dt], 0, 0, 0);
      }
    }
  }

  // epilogue: store UNNORMALIZED bf16 partial ctx + f32 partial l (merged in merge_kernel)
  __bf16* cout = kvh ? c1 : c0;
  float* lout = lp + kvh * 65536;
#pragma unroll
  for (int st = 0; st < 2; ++st) {
#pragma unroll
    for (int dt = 0; dt < 4; ++dt)
#pragma unroll
      for (int rr = 0; rr < 4; ++rr)
        cout[(size_t)(b * 2048 + qw + st * 16 + quad * 4 + rr) * 1024 + h * 64 + dt * 16 + l15] =
            (__bf16)acc[st][dt][rr];
    if (l15 == 0) {
#pragma unroll
      for (int rr = 0; rr < 4; ++rr)
        lout[(size_t)(b * 2048 + qw + st * 16 + quad * 4 + rr) * 16 + h] = acc_l[st][rr];
    }
  }
}

extern "C" void kernel_launch(void* const* d_in, const int* in_sizes, int n_in,
                              void* d_out, int out_size, void* d_ws, size_t ws_size,
                              hipStream_t stream) {
  const float* X  = (const float*)d_in[0];
  const int* mask = (const int*)d_in[1];
  const float* Wq = (const float*)d_in[2];
  const float* Wk = (const float*)d_in[3];
  const float* Wv = (const float*)d_in[4];
  const float* Wo = (const float*)d_in[5];

  __bf16* w   = (__bf16*)d_ws;
  __bf16* Xbf = w;                  // 4096*1024
  __bf16* Wqb = Xbf + 4194304;      // 1024*1024 each
  __bf16* Wkb = Wqb + 1048576;
  __bf16* Wvb = Wkb + 1048576;
  __bf16* Wob = Wvb + 1048576;
  __bf16* Qb  = Wob + 1048576;      // 4096*1024
  __bf16* Kb  = Qb + 4194304;
  __bf16* Vtb = Kb + 4194304;       // 1024*4096 (transposed V)
  __bf16* Ctx = Vtb + 4194304;      // 4096*1024 (half-0 partial, then merged)
  // extra workspace past Ctx for the packed mask + l partials (clear of all live data)
  unsigned long long* pmt = (unsigned long long*)(Ctx + 4194304);  // 1 MB
  float* lpart = (float*)(pmt + 131072);                           // 512 KB [2][4096][16]
  __bf16* c1 = Xbf;  // half-1 partial reuses Xbf (dead after qkv_gemm)

  prep_kernel<<<40960, 256, 0, stream>>>(X, Wq, Wk, Wv, Wo, mask,
                                         Xbf, Wqb, Wkb, Wvb, Wob, pmt);
  qkv_gemm<<<dim3(256, 3), 256, 0, stream>>>(Xbf, Wqb, Wkb, Wvb, Qb, Kb, Vtb);
  attn_kernel<<<1024, 256, 0, stream>>>(Qb, Kb, Vtb, pmt, Ctx, c1, lpart);
  merge_kernel<<<2048, 256, 0, stream>>>(Ctx, c1, lpart, Ctx);
  out_gemm<<<256, 256, 0, stream>>>(Ctx, Wob, (float*)d_out);
}